// Round 13
// baseline (267.916 us; speedup 1.0000x reference)
//
#include <hip/hip_runtime.h>
#include <math.h>

#define T_SEQ 28
#define D_IN  28
#define H     128
#define NTHR  512
#define NT1   1024

typedef short bf16x8 __attribute__((ext_vector_type(8)));   // 8 bf16 = 4 VGPR (A/B frag)
typedef short bf16x2 __attribute__((ext_vector_type(2)));
typedef float f32x4  __attribute__((ext_vector_type(4)));   // C/D frag
typedef unsigned u32x4 __attribute__((ext_vector_type(4)));

// ws layout: W0 frags [ut][f0:20][lane][8] | W1 frags [ut][f1:32][lane][8] | biases fp32 | h0seq
#define NW0E (8*20*512)                     // 81920 ushorts
#define NW1E (8*32*512)                     // 131072 ushorts
#define BIAS_OFF_BYTES ((NW0E + NW1E) * 2)  // 425984 B
#define SEQ_OFF_BYTES  (BIAS_OFF_BYTES + 4096)
#define SEQ_ELEMS      ((size_t)512 * T_SEQ * 2048)          // bf16 elements
#define NEED_WS        (SEQ_OFF_BYTES + SEQ_ELEMS * 2)       // ~59.2 MB

__device__ __forceinline__ unsigned short f2bf(float f) {
    unsigned u = __float_as_uint(f);
    u += 0x7fffu + ((u >> 16) & 1u);        // round-to-nearest-even
    return (unsigned short)(u >> 16);
}
__device__ __forceinline__ float bf2f(unsigned short h) {
    return __uint_as_float(((unsigned)h) << 16);
}
__device__ __forceinline__ unsigned pkbf2(float a, float b) {
#if __has_builtin(__builtin_amdgcn_cvt_pk_bf16_f32)
    bf16x2 r = __builtin_amdgcn_cvt_pk_bf16_f32(a, b);
    return __builtin_bit_cast(unsigned, r);
#else
    return (unsigned)f2bf(a) | ((unsigned)f2bf(b) << 16);
#endif
}
// Fast activations: v_rcp_f32 (1 ulp) instead of the IEEE div sequence.
__device__ __forceinline__ float frcp(float x)   { return __builtin_amdgcn_rcpf(x); }
__device__ __forceinline__ float sigm(float x)   { return frcp(1.0f + __expf(-x)); }
__device__ __forceinline__ float tanhf_(float x) { return 1.0f - 2.0f * frcp(1.0f + __expf(2.0f * x)); }

// Opaque-def pin: blocks rematerialization of the one-time weight loads.
__device__ __forceinline__ void pin(bf16x8& v) { asm volatile("" : "+v"(v)); }

// LDS-only barrier: cross-wave dependence inside the t-loop is hbuf (LDS) only.
#define LDS_BARRIER() asm volatile("s_waitcnt lgkmcnt(0)\ns_barrier" ::: "memory")

#define MFMA(acc, a, b) acc = __builtin_amdgcn_mfma_f32_16x16x32_bf16(a, b, acc, 0, 0, 0)

// Pack weights into exact B-fragment order: B[k][n], n = lane&15, k = (lane>>4)*8 + j.
__global__ void prep(const float* __restrict__ Wih0, const float* __restrict__ Whh0,
                     const float* __restrict__ bih0, const float* __restrict__ bhh0,
                     const float* __restrict__ Wih1, const float* __restrict__ Whh1,
                     const float* __restrict__ bih1, const float* __restrict__ bhh1,
                     unsigned short* __restrict__ W, float* __restrict__ bias) {
    int i = blockIdx.x * 256 + threadIdx.x;
    if (i < NW0E) {
        int ut = i / (20*512), r = i % (20*512);
        int f = r >> 9, e = r & 511;
        int lane = e >> 3, j = e & 7;
        int lrow = lane & 15, quad = lane >> 4;
        float v;
        if (f < 4) {                        // x-part: K=28 padded to 32
            int gt = f, k = quad*8 + j;
            int g = gt*128 + ut*16 + lrow;
            v = (k < D_IN) ? Wih0[g*D_IN + k] : 0.0f;
        } else {                            // h0-part: 4 K-steps
            int ks = (f-4) >> 2, gt = (f-4) & 3;
            int g = gt*128 + ut*16 + lrow;
            v = Whh0[g*H + ks*32 + quad*8 + j];
        }
        W[i] = f2bf(v);
    } else if (i < NW0E + NW1E) {
        int i2 = i - NW0E;
        int ut = i2 / (32*512), r = i2 % (32*512);
        int f = r >> 9, e = r & 511;
        int lane = e >> 3, j = e & 7;
        int lrow = lane & 15, quad = lane >> 4;
        int ks = f >> 2, gt = f & 3;        // ks 0..3 = Wih1, 4..7 = Whh1
        int g = gt*128 + ut*16 + lrow;
        float v = (ks < 4) ? Wih1[g*H + ks*32 + quad*8 + j]
                           : Whh1[g*H + (ks-4)*32 + quad*8 + j];
        W[i] = f2bf(v);
    } else if (i < NW0E + NW1E + 1024) {
        int g = i - NW0E - NW1E;
        if (g < 512) bias[g] = bih0[g] + bhh0[g];
        else         bias[g] = bih1[g-512] + bhh1[g-512];
    }
}

// ================= Phase kernels ==========
// h0seq layout: [bt16:512][t:28][cc:4][lane:64][el:8] bf16 — exact A-frag order.

// Layer 0: BT=16, grid 512 -> 2 blocks/CU. 16 recurrent frags PINNED (64 regs);
// x-frags in 32 KB LDS. (2,2) -> 128-reg budget (empirical; (4,4) gave 64+spill).
__global__ __attribute__((amdgpu_waves_per_eu(2, 2))) __launch_bounds__(NTHR)
void lstm_l0(
    const float* __restrict__ x, const unsigned short* __restrict__ W,
    const float* __restrict__ bias, unsigned short* __restrict__ h0seq)
{
    __shared__ __align__(16) unsigned short hbuf[2][16*128];  //  8 KB (double buffer)
    __shared__ __align__(16) unsigned short wxl[8*4*512];     // 32 KB: W0 x-part frags

    const int tid = threadIdx.x, lane = tid & 63, ut = tid >> 6;
    const int lrow = lane & 15, quad = lane >> 4;
    const int blk = blockIdx.x;          // bt16 index 0..511
    const int bbase = blk * 16;

    for (int i = tid; i < 16*128; i += NTHR) { hbuf[0][i] = 0; hbuf[1][i] = 0; }
#pragma unroll
    for (int it = 0; it < 4; ++it) {     // stage x-part frags (16384 ushorts)
        int i = it*NTHR + tid;           // chunk id 0..2047
        int utw = i >> 8, rest = i & 255, f = rest >> 6, l8 = rest & 63;
        *(bf16x8*)&wxl[utw*2048 + f*512 + l8*8] =
            *(const bf16x8*)&W[utw*10240 + f*512 + l8*8];
    }

    const unsigned short* w0p = W + ut*10240 + lane*8;
    bf16x8 wh[16];
#pragma unroll
    for (int f = 0; f < 16; ++f) { wh[f] = *(const bf16x8*)(w0p + (4+f)*512); pin(wh[f]); }

    float c0[4] = {0.f,0.f,0.f,0.f};
    float bv[4];
#pragma unroll
    for (int gt = 0; gt < 4; ++gt) bv[gt] = bias[gt*128 + ut*16 + lrow];

    const float* xr = x + (size_t)(bbase + lrow) * (T_SEQ*D_IN) + quad*8;
    const int jc = (ut*16 + lrow) >> 3, jl = (ut*16 + lrow) & 7;

    // coalesced-store mapping (threads 0..255 = waves 0..3)
    const int scc = tid >> 6;            // A-frag cc (valid for tid<256)
    const int sl  = tid & 63;            // A-frag lane'
    const int sq2 = sl >> 4, sb = sl & 15;
    const int schunk = (scc*4 + sq2) ^ sb;           // contiguous hbuf chunk
    unsigned short* sdst = h0seq + (size_t)blk*(T_SEQ*2048) + scc*512 + sl*8;

    // preload x(t=0)
    float4 lo = *(const float4*)xr;
    float4 hi = make_float4(0.f,0.f,0.f,0.f);
    if (quad < 3) hi = *(const float4*)(xr+4);

    __syncthreads();

#pragma unroll 1
    for (int t = 0; t < T_SEQ; ++t) {
        u32x4 ua;
        ua[0]=pkbf2(lo.x,lo.y); ua[1]=pkbf2(lo.z,lo.w);
        ua[2]=pkbf2(hi.x,hi.y); ua[3]=pkbf2(hi.z,hi.w);
        bf16x8 ax = __builtin_bit_cast(bf16x8, ua);

        LDS_BARRIER();                   // prev hbuf writes visible (LDS only)

        const unsigned short* hrd = hbuf[t & 1];
        unsigned short* hwr = hbuf[(t+1) & 1];

        // coalesced h0seq store of h(t-1) (hrd), waves 0..3 only
        if (t > 0 && tid < 256) {
            bf16x8 hv = *(const bf16x8*)&hrd[sb*128 + schunk*8];
            *(bf16x8*)(sdst + (size_t)(t-1)*2048) = hv;
        }

        f32x4 acg[4];
#pragma unroll
        for (int gt = 0; gt < 4; ++gt) { f32x4 s = {bv[gt],bv[gt],bv[gt],bv[gt]}; acg[gt] = s; }
#pragma unroll
        for (int ks = 0; ks < 4; ++ks) {     // recurrent part (pinned reg weights)
            int cc = ks*4 + quad;
            bf16x8 ah = *(const bf16x8*)&hrd[lrow*128 + ((cc ^ lrow)*8)];
#pragma unroll
            for (int gt = 0; gt < 4; ++gt) MFMA(acg[gt], ah, wh[ks*4+gt]);
        }
#pragma unroll
        for (int gt = 0; gt < 4; ++gt) {     // x part (LDS weights)
            bf16x8 wf = *(const bf16x8*)&wxl[ut*2048 + gt*512 + lane*8];
            MFMA(acg[gt], ax, wf);
        }

        // prefetch x(t+1) — latency hidden under elementwise
        if (t + 1 < T_SEQ) {
            const float* p = xr + (t+1)*D_IN;
            lo = *(const float4*)p;
            hi = make_float4(0.f,0.f,0.f,0.f);
            if (quad < 3) hi = *(const float4*)(p+4);
        }

#pragma unroll
        for (int r = 0; r < 4; r += 2) {
            float hv[2];
#pragma unroll
            for (int q = 0; q < 2; ++q) {
                float ig = sigm(acg[0][r+q]);
                float fg = sigm(acg[1][r+q]);
                float gg = tanhf_(acg[2][r+q]);
                float og = sigm(acg[3][r+q]);
                float c  = fg * c0[r+q] + ig * gg;
                c0[r+q] = c;
                hv[q] = og * tanhf_(c);
            }
            unsigned u = pkbf2(hv[0], hv[1]);
            int b0 = quad*4 + r;
            hwr[b0*128     + ((jc ^ b0)*8)     + jl] = (unsigned short)u;
            hwr[(b0+1)*128 + ((jc ^ (b0+1))*8) + jl] = (unsigned short)(u >> 16);
        }
    }

    // final h(T-1) store (in hbuf[T_SEQ & 1] = hbuf[0])
    LDS_BARRIER();
    if (tid < 256) {
        const unsigned short* hrd = hbuf[T_SEQ & 1];
        bf16x8 hv = *(const bf16x8*)&hrd[sb*128 + schunk*8];
        *(bf16x8*)(sdst + (size_t)(T_SEQ-1)*2048) = hv;
    }
}

// Layer 1 + FC + log_softmax: BT=32, grid 256, 1024 thr (16 waves; wave=(ut,mt)).
// Wih1 (16 frags) PINNED (64 regs); Whh1 in 128 KB LDS. (2,2) -> 128-reg budget;
// 4 waves/SIMD at 1 block/CU.
__global__ __attribute__((amdgpu_waves_per_eu(2, 2))) __launch_bounds__(NT1)
void lstm_l1(
    const unsigned short* __restrict__ h0seq, const unsigned short* __restrict__ W,
    const float* __restrict__ bias, const float* __restrict__ Wfc,
    const float* __restrict__ bfc, float* __restrict__ out)
{
    __shared__ __align__(16) unsigned short hbuf[2][32*128];  //  16 KB
    __shared__ __align__(16) unsigned short wl[8*16*512];     // 128 KB: Whh1 frags

    const int tid = threadIdx.x, lane = tid & 63;
    const int wid = tid >> 6, ut = wid >> 1, mt = wid & 1;
    const int lrow = lane & 15, quad = lane >> 4;
    const int blk = blockIdx.x;
    const int bbase = blk * 32;

    for (int i = tid; i < 32*128; i += NT1) { hbuf[0][i] = 0; hbuf[1][i] = 0; }
#pragma unroll
    for (int it = 0; it < 8; ++it) {     // stage Whh1 frags (65536 ushorts = 8192 chunks)
        int c = it*NT1 + tid;            // chunk id 0..8191
        int utw = c >> 10, r = c & 1023; // 1024 chunks per ut
        int f = r >> 6, l8 = r & 63;
        *(bf16x8*)&wl[utw*8192 + f*512 + l8*8] =
            *(const bf16x8*)&W[NW0E + utw*16384 + 8192 + f*512 + l8*8];
    }

    const unsigned short* w1p = W + NW0E + ut*16384 + lane*8;
    bf16x8 w1a[16];                      // Wih1 (ks0..3), pinned
#pragma unroll
    for (int f = 0; f < 16; ++f) { w1a[f] = *(const bf16x8*)(w1p + f*512); pin(w1a[f]); }

    float c1[4] = {0.f,0.f,0.f,0.f};
    float bv1[4];
#pragma unroll
    for (int gt = 0; gt < 4; ++gt) bv1[gt] = bias[512 + gt*128 + ut*16 + lrow];

    const unsigned short* sq = h0seq + (size_t)(2*blk + mt) * (T_SEQ*2048) + lane*8;
    const int jc = (ut*16 + lrow) >> 3, jl = (ut*16 + lrow) & 7;

    // preload ga(t=0)
    bf16x8 ga[4];
#pragma unroll
    for (int cc = 0; cc < 4; ++cc) ga[cc] = *(const bf16x8*)(sq + cc*512);

    __syncthreads();

#pragma unroll 1
    for (int t = 0; t < T_SEQ; ++t) {
        LDS_BARRIER();                   // prev hbuf writes visible (LDS only)

        const unsigned short* hrd = hbuf[t & 1];
        unsigned short* hwr = hbuf[(t+1) & 1];

        f32x4 acg[4];
#pragma unroll
        for (int gt = 0; gt < 4; ++gt) { f32x4 s = {bv1[gt],bv1[gt],bv1[gt],bv1[gt]}; acg[gt] = s; }
#pragma unroll
        for (int ks = 0; ks < 4; ++ks) {     // Whh1 x h1 (LDS weights, LDS A-frags)
            int cc = ks*4 + quad;
            bf16x8 ah = *(const bf16x8*)&hrd[(mt*16+lrow)*128 + ((cc ^ lrow)*8)];
#pragma unroll
            for (int gt = 0; gt < 4; ++gt) {
                bf16x8 wf = *(const bf16x8*)&wl[ut*8192 + (ks*4+gt)*512 + lane*8];
                MFMA(acg[gt], ah, wf);
            }
        }
#pragma unroll
        for (int cc = 0; cc < 4; ++cc)       // Wih1 x h0 (pinned reg weights)
#pragma unroll
            for (int gt = 0; gt < 4; ++gt) MFMA(acg[gt], ga[cc], w1a[cc*4+gt]);

        // prefetch ga(t+1) — latency hidden under elementwise
        if (t + 1 < T_SEQ) {
#pragma unroll
            for (int cc = 0; cc < 4; ++cc) ga[cc] = *(const bf16x8*)(sq + (t+1)*2048 + cc*512);
        }

#pragma unroll
        for (int r = 0; r < 4; r += 2) {
            float hv[2];
#pragma unroll
            for (int q = 0; q < 2; ++q) {
                float ig = sigm(acg[0][r+q]);
                float fg = sigm(acg[1][r+q]);
                float gg = tanhf_(acg[2][r+q]);
                float og = sigm(acg[3][r+q]);
                float c  = fg * c1[r+q] + ig * gg;
                c1[r+q] = c;
                hv[q] = og * tanhf_(c);
            }
            unsigned u = pkbf2(hv[0], hv[1]);
            int b0 = mt*16 + quad*4 + r;
            hwr[b0*128     + ((jc ^ (b0&15))*8)     + jl] = (unsigned short)u;
            hwr[(b0+1)*128 + ((jc ^ ((b0+1)&15))*8) + jl] = (unsigned short)(u >> 16);
        }
    }

    __syncthreads();   // final h1 (hbuf[0], T_SEQ even) visible

    float* lg = (float*)&hbuf[1][0];     // overlay dead buffer
    if (tid < 320) {
        int c = tid >> 5, b = tid & 31;
        float s = bfc[c];
        const float* wr = Wfc + c*H;
#pragma unroll 4
        for (int j = 0; j < H; ++j)
            s = fmaf(wr[j], bf2f(hbuf[0][b*128 + (((j>>3) ^ (b&15))*8) + (j&7)]), s);
        lg[c*32 + b] = s;
    }
    __syncthreads();
    if (tid < 32) {
        int b = tid;
        float m = -1e30f;
#pragma unroll
        for (int c = 0; c < 10; ++c) m = fmaxf(m, lg[c*32 + b]);
        float ssum = 0.f;
#pragma unroll
        for (int c = 0; c < 10; ++c) ssum += __expf(lg[c*32 + b] - m);
        float ls = m + __logf(ssum);
        float* op = out + (size_t)(bbase + b) * 10;
#pragma unroll
        for (int c = 0; c < 10; ++c) op[c] = lg[c*32 + b] - ls;
    }
}

// ================= Monolithic fallback =====================
__global__ __attribute__((amdgpu_waves_per_eu(2, 2))) __launch_bounds__(NTHR)
void lstm_mfma(
    const float* __restrict__ x, const unsigned short* __restrict__ W,
    const float* __restrict__ bias,
    const float* __restrict__ Wfc, const float* __restrict__ bfc,
    float* __restrict__ out)
{
    __shared__ __align__(16) unsigned short h0s[2][32*128];
    __shared__ __align__(16) unsigned short h1s[32*128];
    __shared__ __align__(16) unsigned short wl[8*16*512];

    const int tid  = threadIdx.x;
    const int lane = tid & 63;
    const int ut   = tid >> 6;
    const int lrow = lane & 15;
    const int quad = lane >> 4;
    const int bbase = blockIdx.x * 32;

    for (int i = tid; i < 32*128; i += NTHR) { h0s[0][i] = 0; h0s[1][i] = 0; h1s[i] = 0; }
#pragma unroll
    for (int it = 0; it < 16; ++it) {
        int i = it * (NTHR*8) + tid*8;
        int utw = i >> 13, r = i & 8191;
        *(bf16x8*)&wl[i] = *(const bf16x8*)&W[NW0E + utw*16384 + 8192 + r];
    }
    const unsigned short* w0p = W + ut*(20*512) + lane*8;
    const unsigned short* w1p = W + NW0E + ut*(32*512) + lane*8;
    bf16x8 w0x[4], w0h[16], w1h[16];
#pragma unroll
    for (int f = 0; f < 4; ++f)  w0x[f] = *(const bf16x8*)(w0p + f*512);
#pragma unroll
    for (int f = 0; f < 16; ++f) w0h[f] = *(const bf16x8*)(w0p + (4+f)*512);
#pragma unroll
    for (int f = 0; f < 16; ++f) w1h[f] = *(const bf16x8*)(w1p + f*512);

    float c0[2][4], c1[2][4];
#pragma unroll
    for (int m = 0; m < 2; ++m)
#pragma unroll
        for (int r = 0; r < 4; ++r) { c0[m][r] = 0.f; c1[m][r] = 0.f; }
    float bv0[4], bv1[4];
#pragma unroll
    for (int gt = 0; gt < 4; ++gt) {
        bv0[gt] = bias[gt*128 + ut*16 + lrow];
        bv1[gt] = bias[512 + gt*128 + ut*16 + lrow];
    }
    const float* xr0 = x + (size_t)(bbase + lrow)      * (T_SEQ*D_IN) + quad*8;
    const float* xr1 = x + (size_t)(bbase + 16 + lrow) * (T_SEQ*D_IN) + quad*8;
    const int jc = (ut*16 + lrow) >> 3;
    const int jl = (ut*16 + lrow) & 7;
    __syncthreads();

    auto step = [&](const unsigned short* __restrict__ h0rd,
                    unsigned short* __restrict__ h0wr, int t) {
        f32x4 acc[2][4];
#pragma unroll
        for (int gt = 0; gt < 4; ++gt) {
            f32x4 s = {bv0[gt], bv0[gt], bv0[gt], bv0[gt]};
            acc[0][gt] = s; acc[1][gt] = s;
        }
        {
            const float* p0 = xr0 + t*D_IN;
            const float* p1 = xr1 + t*D_IN;
            float4 lo0 = *(const float4*)p0;
            float4 lo1 = *(const float4*)p1;
            float4 hi0 = make_float4(0,0,0,0), hi1 = make_float4(0,0,0,0);
            if (quad < 3) { hi0 = *(const float4*)(p0+4); hi1 = *(const float4*)(p1+4); }
            u32x4 ua0, ua1;
            ua0[0] = pkbf2(lo0.x, lo0.y); ua0[1] = pkbf2(lo0.z, lo0.w);
            ua0[2] = pkbf2(hi0.x, hi0.y); ua0[3] = pkbf2(hi0.z, hi0.w);
            ua1[0] = pkbf2(lo1.x, lo1.y); ua1[1] = pkbf2(lo1.z, lo1.w);
            ua1[2] = pkbf2(hi1.x, hi1.y); ua1[3] = pkbf2(hi1.z, hi1.w);
            bf16x8 a0 = __builtin_bit_cast(bf16x8, ua0);
            bf16x8 a1 = __builtin_bit_cast(bf16x8, ua1);
#pragma unroll
            for (int gt = 0; gt < 4; ++gt) {
                MFMA(acc[0][gt], a0, w0x[gt]);
                MFMA(acc[1][gt], a1, w0x[gt]);
            }
        }
#pragma unroll
        for (int ks = 0; ks < 4; ++ks) {
            int cc = ks*4 + quad;
            bf16x8 a0 = *(const bf16x8*)&h0rd[lrow*128      + ((cc ^ lrow)*8)];
            bf16x8 a1 = *(const bf16x8*)&h0rd[(16+lrow)*128 + ((cc ^ lrow)*8)];
#pragma unroll
            for (int gt = 0; gt < 4; ++gt) {
                MFMA(acc[0][gt], a0, w0h[ks*4+gt]);
                MFMA(acc[1][gt], a1, w0h[ks*4+gt]);
            }
        }
#pragma unroll
        for (int m = 0; m < 2; ++m) {
#pragma unroll
            for (int r = 0; r < 4; r += 2) {
                float hv[2];
#pragma unroll
                for (int q = 0; q < 2; ++q) {
                    float ig = sigm(acc[m][0][r+q]);
                    float fg = sigm(acc[m][1][r+q]);
                    float gg = tanhf_(acc[m][2][r+q]);
                    float og = sigm(acc[m][3][r+q]);
                    float c  = fg * c0[m][r+q] + ig * gg;
                    c0[m][r+q] = c;
                    hv[q] = og * tanhf_(c);
                }
                unsigned u = pkbf2(hv[0], hv[1]);
                int b0 = m*16 + quad*4 + r;
                h0wr[b0*128     + ((jc ^ (b0&15))*8)     + jl] = (unsigned short)u;
                h0wr[(b0+1)*128 + ((jc ^ ((b0+1)&15))*8) + jl] = (unsigned short)(u >> 16);
            }
        }
        __syncthreads();
#pragma unroll
        for (int gt = 0; gt < 4; ++gt) {
            f32x4 s = {bv1[gt], bv1[gt], bv1[gt], bv1[gt]};
            acc[0][gt] = s; acc[1][gt] = s;
        }
#pragma unroll
        for (int ks = 0; ks < 4; ++ks) {
            int cc = ks*4 + quad;
            bf16x8 a0 = *(const bf16x8*)&h0wr[lrow*128      + ((cc ^ lrow)*8)];
            bf16x8 a1 = *(const bf16x8*)&h0wr[(16+lrow)*128 + ((cc ^ lrow)*8)];
#pragma unroll
            for (int gt = 0; gt < 4; ++gt) {
                MFMA(acc[0][gt], a0, w1h[ks*4+gt]);
                MFMA(acc[1][gt], a1, w1h[ks*4+gt]);
            }
        }
#pragma unroll
        for (int ks = 0; ks < 4; ++ks) {
            int cc = ks*4 + quad;
            bf16x8 a0 = *(const bf16x8*)&h1s[lrow*128      + ((cc ^ lrow)*8)];
            bf16x8 a1 = *(const bf16x8*)&h1s[(16+lrow)*128 + ((cc ^ lrow)*8)];
#pragma unroll
            for (int gt = 0; gt < 4; ++gt) {
                bf16x8 bf = *(const bf16x8*)&wl[ut*8192 + (ks*4+gt)*512 + lane*8];
                MFMA(acc[0][gt], a0, bf);
                MFMA(acc[1][gt], a1, bf);
            }
        }
        __syncthreads();
#pragma unroll
        for (int m = 0; m < 2; ++m) {
#pragma unroll
            for (int r = 0; r < 4; r += 2) {
                float hv[2];
#pragma unroll
                for (int q = 0; q < 2; ++q) {
                    float ig = sigm(acc[m][0][r+q]);
                    float fg = sigm(acc[m][1][r+q]);
                    float gg = tanhf_(acc[m][2][r+q]);
                    float og = sigm(acc[m][3][r+q]);
                    float c  = fg * c1[m][r+q] + ig * gg;
                    c1[m][r+q] = c;
                    hv[q] = og * tanhf_(c);
                }
                unsigned u = pkbf2(hv[0], hv[1]);
                int b0 = m*16 + quad*4 + r;
                h1s[b0*128     + ((jc ^ (b0&15))*8)     + jl] = (unsigned short)u;
                h1s[(b0+1)*128 + ((jc ^ ((b0+1)&15))*8) + jl] = (unsigned short)(u >> 16);
            }
        }
    };
#pragma unroll 1
    for (int t2 = 0; t2 < T_SEQ/2; ++t2) {
        step(h0s[0], h0s[1], 2*t2);
        step(h0s[1], h0s[0], 2*t2 + 1);
    }
    __syncthreads();
    float* lg = (float*)&h0s[0][0];
    if (tid < 320) {
        int c = tid >> 5, b = tid & 31;
        float s = bfc[c];
        const float* wr = Wfc + c*H;
#pragma unroll 4
        for (int j = 0; j < H; ++j)
            s = fmaf(wr[j], bf2f(h1s[b*128 + (((j>>3) ^ (b&15))*8) + (j&7)]), s);
        lg[c*32 + b] = s;
    }
    __syncthreads();
    if (tid < 32) {
        int b = tid;
        float m = -1e30f;
#pragma unroll
        for (int c = 0; c < 10; ++c) m = fmaxf(m, lg[c*32 + b]);
        float ssum = 0.f;
#pragma unroll
        for (int c = 0; c < 10; ++c) ssum += __expf(lg[c*32 + b] - m);
        float ls = m + __logf(ssum);
        float* op = out + (size_t)(bbase + b) * 10;
#pragma unroll
        for (int c = 0; c < 10; ++c) op[c] = lg[c*32 + b] - ls;
    }
}

extern "C" void kernel_launch(void* const* d_in, const int* in_sizes, int n_in,
                              void* d_out, int out_size, void* d_ws, size_t ws_size,
                              hipStream_t stream) {
    const float* x    = (const float*)d_in[0];
    const float* Wih0 = (const float*)d_in[1];
    const float* Whh0 = (const float*)d_in[2];
    const float* bih0 = (const float*)d_in[3];
    const float* bhh0 = (const float*)d_in[4];
    const float* Wih1 = (const float*)d_in[5];
    const float* Whh1 = (const float*)d_in[6];
    const float* bih1 = (const float*)d_in[7];
    const float* bhh1 = (const float*)d_in[8];
    const float* Wfc  = (const float*)d_in[9];
    const float* bfc  = (const float*)d_in[10];
    float* out = (float*)d_out;

    unsigned short* W = (unsigned short*)d_ws;
    float* bias = (float*)((char*)d_ws + BIAS_OFF_BYTES);

    const int n_prep = NW0E + NW1E + 1024;
    prep<<<(n_prep + 255) / 256, 256, 0, stream>>>(Wih0, Whh0, bih0, bhh0,
                                                   Wih1, Whh1, bih1, bhh1, W, bias);
    if (ws_size >= (size_t)NEED_WS) {
        unsigned short* h0seq = (unsigned short*)((char*)d_ws + SEQ_OFF_BYTES);
        lstm_l0<<<512, NTHR, 0, stream>>>(x, W, bias, h0seq);
        lstm_l1<<<256, NT1, 0, stream>>>(h0seq, W, bias, Wfc, bfc, out);
    } else {
        lstm_mfma<<<256, NTHR, 0, stream>>>(x, W, bias, Wfc, bfc, out);
    }
}

// Round 14
// 220.922 us; speedup vs baseline: 1.2127x; 1.2127x over previous
//
#include <hip/hip_runtime.h>
#include <math.h>

#define T_SEQ 28
#define D_IN  28
#define H     128
#define NTHR  512

typedef short bf16x8 __attribute__((ext_vector_type(8)));   // 8 bf16 = 4 VGPR (A/B frag)
typedef short bf16x2 __attribute__((ext_vector_type(2)));
typedef float f32x4  __attribute__((ext_vector_type(4)));   // C/D frag
typedef unsigned u32x4 __attribute__((ext_vector_type(4)));

// ws layout: W0 frags [ut][f0:20][lane][8] | W1 frags [ut][f1:32][lane][8] | biases fp32 | h0seq
#define NW0E (8*20*512)                     // 81920 ushorts
#define NW1E (8*32*512)                     // 131072 ushorts
#define BIAS_OFF_BYTES ((NW0E + NW1E) * 2)  // 425984 B
#define SEQ_OFF_BYTES  (BIAS_OFF_BYTES + 4096)
#define SEQ_ELEMS      ((size_t)512 * T_SEQ * 2048)          // bf16 elements
#define NEED_WS        (SEQ_OFF_BYTES + SEQ_ELEMS * 2)       // ~59.2 MB

__device__ __forceinline__ unsigned short f2bf(float f) {
    unsigned u = __float_as_uint(f);
    u += 0x7fffu + ((u >> 16) & 1u);        // round-to-nearest-even
    return (unsigned short)(u >> 16);
}
__device__ __forceinline__ float bf2f(unsigned short h) {
    return __uint_as_float(((unsigned)h) << 16);
}
__device__ __forceinline__ unsigned pkbf2(float a, float b) {
#if __has_builtin(__builtin_amdgcn_cvt_pk_bf16_f32)
    bf16x2 r = __builtin_amdgcn_cvt_pk_bf16_f32(a, b);
    return __builtin_bit_cast(unsigned, r);
#else
    return (unsigned)f2bf(a) | ((unsigned)f2bf(b) << 16);
#endif
}
// Fast activations: v_rcp_f32 (1 ulp) instead of the IEEE div sequence.
__device__ __forceinline__ float frcp(float x)   { return __builtin_amdgcn_rcpf(x); }
__device__ __forceinline__ float sigm(float x)   { return frcp(1.0f + __expf(-x)); }
__device__ __forceinline__ float tanhf_(float x) { return 1.0f - 2.0f * frcp(1.0f + __expf(2.0f * x)); }

// Opaque-def pin: blocks rematerialization of the one-time weight loads.
__device__ __forceinline__ void pin(bf16x8& v) { asm volatile("" : "+v"(v)); }

// LDS-only barrier: cross-wave dependence inside the t-loop is hbuf (LDS) only.
#define LDS_BARRIER() asm volatile("s_waitcnt lgkmcnt(0)\ns_barrier" ::: "memory")

#define MFMA(acc, a, b) acc = __builtin_amdgcn_mfma_f32_16x16x32_bf16(a, b, acc, 0, 0, 0)

// Pack weights into exact B-fragment order: B[k][n], n = lane&15, k = (lane>>4)*8 + j.
__global__ void prep(const float* __restrict__ Wih0, const float* __restrict__ Whh0,
                     const float* __restrict__ bih0, const float* __restrict__ bhh0,
                     const float* __restrict__ Wih1, const float* __restrict__ Whh1,
                     const float* __restrict__ bih1, const float* __restrict__ bhh1,
                     unsigned short* __restrict__ W, float* __restrict__ bias) {
    int i = blockIdx.x * 256 + threadIdx.x;
    if (i < NW0E) {
        int ut = i / (20*512), r = i % (20*512);
        int f = r >> 9, e = r & 511;
        int lane = e >> 3, j = e & 7;
        int lrow = lane & 15, quad = lane >> 4;
        float v;
        if (f < 4) {                        // x-part: K=28 padded to 32
            int gt = f, k = quad*8 + j;
            int g = gt*128 + ut*16 + lrow;
            v = (k < D_IN) ? Wih0[g*D_IN + k] : 0.0f;
        } else {                            // h0-part: 4 K-steps
            int ks = (f-4) >> 2, gt = (f-4) & 3;
            int g = gt*128 + ut*16 + lrow;
            v = Whh0[g*H + ks*32 + quad*8 + j];
        }
        W[i] = f2bf(v);
    } else if (i < NW0E + NW1E) {
        int i2 = i - NW0E;
        int ut = i2 / (32*512), r = i2 % (32*512);
        int f = r >> 9, e = r & 511;
        int lane = e >> 3, j = e & 7;
        int lrow = lane & 15, quad = lane >> 4;
        int ks = f >> 2, gt = f & 3;        // ks 0..3 = Wih1, 4..7 = Whh1
        int g = gt*128 + ut*16 + lrow;
        float v = (ks < 4) ? Wih1[g*H + ks*32 + quad*8 + j]
                           : Whh1[g*H + (ks-4)*32 + quad*8 + j];
        W[i] = f2bf(v);
    } else if (i < NW0E + NW1E + 1024) {
        int g = i - NW0E - NW1E;
        if (g < 512) bias[g] = bih0[g] + bhh0[g];
        else         bias[g] = bih1[g-512] + bhh1[g-512];
    }
}

// ================= Phase kernels ==========
// h0seq layout: [bt16:512][t:28][cc:4][lane:64][el:8] bf16 — exact A-frag order.

// Layer 0: BT=16, grid 512 -> 2 blocks/CU. 16 recurrent frags PINNED (64 regs);
// x-frags in 32 KB LDS. Block=512 + (2,2) -> 128-reg budget (empirical rule).
__global__ __attribute__((amdgpu_waves_per_eu(2, 2))) __launch_bounds__(NTHR)
void lstm_l0(
    const float* __restrict__ x, const unsigned short* __restrict__ W,
    const float* __restrict__ bias, unsigned short* __restrict__ h0seq)
{
    __shared__ __align__(16) unsigned short hbuf[2][16*128];  //  8 KB (double buffer)
    __shared__ __align__(16) unsigned short wxl[8*4*512];     // 32 KB: W0 x-part frags

    const int tid = threadIdx.x, lane = tid & 63, ut = tid >> 6;
    const int lrow = lane & 15, quad = lane >> 4;
    const int blk = blockIdx.x;          // bt16 index 0..511
    const int bbase = blk * 16;

    for (int i = tid; i < 16*128; i += NTHR) { hbuf[0][i] = 0; hbuf[1][i] = 0; }
#pragma unroll
    for (int it = 0; it < 4; ++it) {     // stage x-part frags (16384 ushorts)
        int i = it*NTHR + tid;           // chunk id 0..2047
        int utw = i >> 8, rest = i & 255, f = rest >> 6, l8 = rest & 63;
        *(bf16x8*)&wxl[utw*2048 + f*512 + l8*8] =
            *(const bf16x8*)&W[utw*10240 + f*512 + l8*8];
    }

    const unsigned short* w0p = W + ut*10240 + lane*8;
    bf16x8 wh[16];
#pragma unroll
    for (int f = 0; f < 16; ++f) { wh[f] = *(const bf16x8*)(w0p + (4+f)*512); pin(wh[f]); }

    float c0[4] = {0.f,0.f,0.f,0.f};
    float bv[4];
#pragma unroll
    for (int gt = 0; gt < 4; ++gt) bv[gt] = bias[gt*128 + ut*16 + lrow];

    const float* xr = x + (size_t)(bbase + lrow) * (T_SEQ*D_IN) + quad*8;
    const int jc = (ut*16 + lrow) >> 3, jl = (ut*16 + lrow) & 7;

    // coalesced-store mapping (threads 0..255 = waves 0..3)
    const int scc = tid >> 6;            // A-frag cc (valid for tid<256)
    const int sl  = tid & 63;            // A-frag lane'
    const int sq2 = sl >> 4, sb = sl & 15;
    const int schunk = (scc*4 + sq2) ^ sb;           // contiguous hbuf chunk
    unsigned short* sdst = h0seq + (size_t)blk*(T_SEQ*2048) + scc*512 + sl*8;

    // preload x(t=0)
    float4 lo = *(const float4*)xr;
    float4 hi = make_float4(0.f,0.f,0.f,0.f);
    if (quad < 3) hi = *(const float4*)(xr+4);

    __syncthreads();

#pragma unroll 1
    for (int t = 0; t < T_SEQ; ++t) {
        u32x4 ua;
        ua[0]=pkbf2(lo.x,lo.y); ua[1]=pkbf2(lo.z,lo.w);
        ua[2]=pkbf2(hi.x,hi.y); ua[3]=pkbf2(hi.z,hi.w);
        bf16x8 ax = __builtin_bit_cast(bf16x8, ua);

        LDS_BARRIER();                   // prev hbuf writes visible (LDS only)

        const unsigned short* hrd = hbuf[t & 1];
        unsigned short* hwr = hbuf[(t+1) & 1];

        // coalesced h0seq store of h(t-1) (hrd), waves 0..3 only
        if (t > 0 && tid < 256) {
            bf16x8 hv = *(const bf16x8*)&hrd[sb*128 + schunk*8];
            *(bf16x8*)(sdst + (size_t)(t-1)*2048) = hv;
        }

        f32x4 acg[4];
#pragma unroll
        for (int gt = 0; gt < 4; ++gt) { f32x4 s = {bv[gt],bv[gt],bv[gt],bv[gt]}; acg[gt] = s; }
#pragma unroll
        for (int ks = 0; ks < 4; ++ks) {     // recurrent part (pinned reg weights)
            int cc = ks*4 + quad;
            bf16x8 ah = *(const bf16x8*)&hrd[lrow*128 + ((cc ^ lrow)*8)];
#pragma unroll
            for (int gt = 0; gt < 4; ++gt) MFMA(acg[gt], ah, wh[ks*4+gt]);
        }
#pragma unroll
        for (int gt = 0; gt < 4; ++gt) {     // x part (LDS weights)
            bf16x8 wf = *(const bf16x8*)&wxl[ut*2048 + gt*512 + lane*8];
            MFMA(acg[gt], ax, wf);
        }

        // prefetch x(t+1) — latency hidden under elementwise
        if (t + 1 < T_SEQ) {
            const float* p = xr + (t+1)*D_IN;
            lo = *(const float4*)p;
            hi = make_float4(0.f,0.f,0.f,0.f);
            if (quad < 3) hi = *(const float4*)(p+4);
        }

#pragma unroll
        for (int r = 0; r < 4; r += 2) {
            float hv[2];
#pragma unroll
            for (int q = 0; q < 2; ++q) {
                float ig = sigm(acg[0][r+q]);
                float fg = sigm(acg[1][r+q]);
                float gg = tanhf_(acg[2][r+q]);
                float og = sigm(acg[3][r+q]);
                float c  = fg * c0[r+q] + ig * gg;
                c0[r+q] = c;
                hv[q] = og * tanhf_(c);
            }
            unsigned u = pkbf2(hv[0], hv[1]);
            int b0 = quad*4 + r;
            hwr[b0*128     + ((jc ^ b0)*8)     + jl] = (unsigned short)u;
            hwr[(b0+1)*128 + ((jc ^ (b0+1))*8) + jl] = (unsigned short)(u >> 16);
        }
    }

    // final h(T-1) store (in hbuf[T_SEQ & 1] = hbuf[0])
    LDS_BARRIER();
    if (tid < 256) {
        const unsigned short* hrd = hbuf[T_SEQ & 1];
        bf16x8 hv = *(const bf16x8*)&hrd[sb*128 + schunk*8];
        *(bf16x8*)(sdst + (size_t)(T_SEQ-1)*2048) = hv;
    }
}

// Layer 1 + FC + log_softmax: BT=32, grid 256, 512 thr (proven R12 config:
// VGPR 124, zero scratch). ALL 32 weight frags PINNED. ga-MFMAs issued FIRST
// (register operands, no LDS dep) to cover the h1 ds_read latency.
__global__ __attribute__((amdgpu_waves_per_eu(2, 2))) __launch_bounds__(NTHR)
void lstm_l1(
    const unsigned short* __restrict__ h0seq, const unsigned short* __restrict__ W,
    const float* __restrict__ bias, const float* __restrict__ Wfc,
    const float* __restrict__ bfc, float* __restrict__ out)
{
    __shared__ __align__(16) unsigned short hbuf[2][32*128];  // 16 KB

    const int tid = threadIdx.x, lane = tid & 63, ut = tid >> 6;
    const int lrow = lane & 15, quad = lane >> 4;
    const int blk = blockIdx.x;
    const int bbase = blk * 32;

    for (int i = tid; i < 32*128; i += NTHR) { hbuf[0][i] = 0; hbuf[1][i] = 0; }

    const unsigned short* w1p = W + NW0E + ut*16384 + lane*8;
    bf16x8 w1a[16], w1b[16];                 // Wih1 (ks0..3), Whh1 (ks4..7)
#pragma unroll
    for (int f = 0; f < 16; ++f) { w1a[f] = *(const bf16x8*)(w1p + f*512);        pin(w1a[f]); }
#pragma unroll
    for (int f = 0; f < 16; ++f) { w1b[f] = *(const bf16x8*)(w1p + (16+f)*512);   pin(w1b[f]); }

    float c1a[4] = {0.f,0.f,0.f,0.f}, c1b[4] = {0.f,0.f,0.f,0.f};
    float bv1[4];
#pragma unroll
    for (int gt = 0; gt < 4; ++gt) bv1[gt] = bias[512 + gt*128 + ut*16 + lrow];

    const unsigned short* sq0 = h0seq + (size_t)(2*blk)   * (T_SEQ*2048) + lane*8;
    const unsigned short* sq1 = h0seq + (size_t)(2*blk+1) * (T_SEQ*2048) + lane*8;
    const int jc = (ut*16 + lrow) >> 3, jl = (ut*16 + lrow) & 7;

    // preload ga(t=0)
    bf16x8 ga0[4], ga1[4];
#pragma unroll
    for (int cc = 0; cc < 4; ++cc) ga0[cc] = *(const bf16x8*)(sq0 + cc*512);
#pragma unroll
    for (int cc = 0; cc < 4; ++cc) ga1[cc] = *(const bf16x8*)(sq1 + cc*512);

    __syncthreads();

#pragma unroll 1
    for (int t = 0; t < T_SEQ; ++t) {
        LDS_BARRIER();                   // prev hbuf writes visible (LDS only)

        const unsigned short* hrd = hbuf[t & 1];
        unsigned short* hwr = hbuf[(t+1) & 1];

        f32x4 acc[2][4];
#pragma unroll
        for (int gt = 0; gt < 4; ++gt) {
            f32x4 s = {bv1[gt],bv1[gt],bv1[gt],bv1[gt]};
            acc[0][gt] = s; acc[1][gt] = s;
        }
#pragma unroll
        for (int cc = 0; cc < 4; ++cc) {     // Wih1 x h0 FIRST (all-register operands)
#pragma unroll
            for (int gt = 0; gt < 4; ++gt) {
                MFMA(acc[0][gt], ga0[cc], w1a[cc*4+gt]);
                MFMA(acc[1][gt], ga1[cc], w1a[cc*4+gt]);
            }
        }
#pragma unroll
        for (int ks = 0; ks < 4; ++ks) {     // Whh1 x h1 (LDS A-frags, latency covered)
            int cc = ks*4 + quad;
            bf16x8 a0 = *(const bf16x8*)&hrd[lrow*128      + ((cc ^ lrow)*8)];
            bf16x8 a1 = *(const bf16x8*)&hrd[(16+lrow)*128 + ((cc ^ lrow)*8)];
#pragma unroll
            for (int gt = 0; gt < 4; ++gt) {
                MFMA(acc[0][gt], a0, w1b[ks*4+gt]);
                MFMA(acc[1][gt], a1, w1b[ks*4+gt]);
            }
        }

        // prefetch ga(t+1) — latency hidden under elementwise
        if (t + 1 < T_SEQ) {
#pragma unroll
            for (int cc = 0; cc < 4; ++cc) ga0[cc] = *(const bf16x8*)(sq0 + (t+1)*2048 + cc*512);
#pragma unroll
            for (int cc = 0; cc < 4; ++cc) ga1[cc] = *(const bf16x8*)(sq1 + (t+1)*2048 + cc*512);
        }

#pragma unroll
        for (int m = 0; m < 2; ++m) {
            float* cst = m ? c1b : c1a;
#pragma unroll
            for (int r = 0; r < 4; r += 2) {
                float hv[2];
#pragma unroll
                for (int q = 0; q < 2; ++q) {
                    float ig = sigm(acc[m][0][r+q]);
                    float fg = sigm(acc[m][1][r+q]);
                    float gg = tanhf_(acc[m][2][r+q]);
                    float og = sigm(acc[m][3][r+q]);
                    float c  = fg * cst[r+q] + ig * gg;
                    cst[r+q] = c;
                    hv[q] = og * tanhf_(c);
                }
                unsigned u = pkbf2(hv[0], hv[1]);
                int b0 = m*16 + quad*4 + r;
                hwr[b0*128     + ((jc ^ (b0&15))*8)     + jl] = (unsigned short)u;
                hwr[(b0+1)*128 + ((jc ^ ((b0+1)&15))*8) + jl] = (unsigned short)(u >> 16);
            }
        }
    }

    __syncthreads();   // final h1 (hbuf[0], T_SEQ even) visible

    float* lg = (float*)&hbuf[1][0];     // overlay dead buffer
    if (tid < 320) {
        int c = tid >> 5, b = tid & 31;
        float s = bfc[c];
        const float* wr = Wfc + c*H;
#pragma unroll 4
        for (int j = 0; j < H; ++j)
            s = fmaf(wr[j], bf2f(hbuf[0][b*128 + (((j>>3) ^ (b&15))*8) + (j&7)]), s);
        lg[c*32 + b] = s;
    }
    __syncthreads();
    if (tid < 32) {
        int b = tid;
        float m = -1e30f;
#pragma unroll
        for (int c = 0; c < 10; ++c) m = fmaxf(m, lg[c*32 + b]);
        float ssum = 0.f;
#pragma unroll
        for (int c = 0; c < 10; ++c) ssum += __expf(lg[c*32 + b] - m);
        float ls = m + __logf(ssum);
        float* op = out + (size_t)(bbase + b) * 10;
#pragma unroll
        for (int c = 0; c < 10; ++c) op[c] = lg[c*32 + b] - ls;
    }
}

// ================= Monolithic fallback =====================
__global__ __attribute__((amdgpu_waves_per_eu(2, 2))) __launch_bounds__(NTHR)
void lstm_mfma(
    const float* __restrict__ x, const unsigned short* __restrict__ W,
    const float* __restrict__ bias,
    const float* __restrict__ Wfc, const float* __restrict__ bfc,
    float* __restrict__ out)
{
    __shared__ __align__(16) unsigned short h0s[2][32*128];
    __shared__ __align__(16) unsigned short h1s[32*128];
    __shared__ __align__(16) unsigned short wl[8*16*512];

    const int tid  = threadIdx.x;
    const int lane = tid & 63;
    const int ut   = tid >> 6;
    const int lrow = lane & 15;
    const int quad = lane >> 4;
    const int bbase = blockIdx.x * 32;

    for (int i = tid; i < 32*128; i += NTHR) { h0s[0][i] = 0; h0s[1][i] = 0; h1s[i] = 0; }
#pragma unroll
    for (int it = 0; it < 16; ++it) {
        int i = it * (NTHR*8) + tid*8;
        int utw = i >> 13, r = i & 8191;
        *(bf16x8*)&wl[i] = *(const bf16x8*)&W[NW0E + utw*16384 + 8192 + r];
    }
    const unsigned short* w0p = W + ut*(20*512) + lane*8;
    const unsigned short* w1p = W + NW0E + ut*(32*512) + lane*8;
    bf16x8 w0x[4], w0h[16], w1h[16];
#pragma unroll
    for (int f = 0; f < 4; ++f)  w0x[f] = *(const bf16x8*)(w0p + f*512);
#pragma unroll
    for (int f = 0; f < 16; ++f) w0h[f] = *(const bf16x8*)(w0p + (4+f)*512);
#pragma unroll
    for (int f = 0; f < 16; ++f) w1h[f] = *(const bf16x8*)(w1p + f*512);

    float c0[2][4], c1[2][4];
#pragma unroll
    for (int m = 0; m < 2; ++m)
#pragma unroll
        for (int r = 0; r < 4; ++r) { c0[m][r] = 0.f; c1[m][r] = 0.f; }
    float bv0[4], bv1[4];
#pragma unroll
    for (int gt = 0; gt < 4; ++gt) {
        bv0[gt] = bias[gt*128 + ut*16 + lrow];
        bv1[gt] = bias[512 + gt*128 + ut*16 + lrow];
    }
    const float* xr0 = x + (size_t)(bbase + lrow)      * (T_SEQ*D_IN) + quad*8;
    const float* xr1 = x + (size_t)(bbase + 16 + lrow) * (T_SEQ*D_IN) + quad*8;
    const int jc = (ut*16 + lrow) >> 3;
    const int jl = (ut*16 + lrow) & 7;
    __syncthreads();

    auto step = [&](const unsigned short* __restrict__ h0rd,
                    unsigned short* __restrict__ h0wr, int t) {
        f32x4 acc[2][4];
#pragma unroll
        for (int gt = 0; gt < 4; ++gt) {
            f32x4 s = {bv0[gt], bv0[gt], bv0[gt], bv0[gt]};
            acc[0][gt] = s; acc[1][gt] = s;
        }
        {
            const float* p0 = xr0 + t*D_IN;
            const float* p1 = xr1 + t*D_IN;
            float4 lo0 = *(const float4*)p0;
            float4 lo1 = *(const float4*)p1;
            float4 hi0 = make_float4(0,0,0,0), hi1 = make_float4(0,0,0,0);
            if (quad < 3) { hi0 = *(const float4*)(p0+4); hi1 = *(const float4*)(p1+4); }
            u32x4 ua0, ua1;
            ua0[0] = pkbf2(lo0.x, lo0.y); ua0[1] = pkbf2(lo0.z, lo0.w);
            ua0[2] = pkbf2(hi0.x, hi0.y); ua0[3] = pkbf2(hi0.z, hi0.w);
            ua1[0] = pkbf2(lo1.x, lo1.y); ua1[1] = pkbf2(lo1.z, lo1.w);
            ua1[2] = pkbf2(hi1.x, hi1.y); ua1[3] = pkbf2(hi1.z, hi1.w);
            bf16x8 a0 = __builtin_bit_cast(bf16x8, ua0);
            bf16x8 a1 = __builtin_bit_cast(bf16x8, ua1);
#pragma unroll
            for (int gt = 0; gt < 4; ++gt) {
                MFMA(acc[0][gt], a0, w0x[gt]);
                MFMA(acc[1][gt], a1, w0x[gt]);
            }
        }
#pragma unroll
        for (int ks = 0; ks < 4; ++ks) {
            int cc = ks*4 + quad;
            bf16x8 a0 = *(const bf16x8*)&h0rd[lrow*128      + ((cc ^ lrow)*8)];
            bf16x8 a1 = *(const bf16x8*)&h0rd[(16+lrow)*128 + ((cc ^ lrow)*8)];
#pragma unroll
            for (int gt = 0; gt < 4; ++gt) {
                MFMA(acc[0][gt], a0, w0h[ks*4+gt]);
                MFMA(acc[1][gt], a1, w0h[ks*4+gt]);
            }
        }
#pragma unroll
        for (int m = 0; m < 2; ++m) {
#pragma unroll
            for (int r = 0; r < 4; r += 2) {
                float hv[2];
#pragma unroll
                for (int q = 0; q < 2; ++q) {
                    float ig = sigm(acc[m][0][r+q]);
                    float fg = sigm(acc[m][1][r+q]);
                    float gg = tanhf_(acc[m][2][r+q]);
                    float og = sigm(acc[m][3][r+q]);
                    float c  = fg * c0[m][r+q] + ig * gg;
                    c0[m][r+q] = c;
                    hv[q] = og * tanhf_(c);
                }
                unsigned u = pkbf2(hv[0], hv[1]);
                int b0 = m*16 + quad*4 + r;
                h0wr[b0*128     + ((jc ^ (b0&15))*8)     + jl] = (unsigned short)u;
                h0wr[(b0+1)*128 + ((jc ^ ((b0+1)&15))*8) + jl] = (unsigned short)(u >> 16);
            }
        }
        __syncthreads();
#pragma unroll
        for (int gt = 0; gt < 4; ++gt) {
            f32x4 s = {bv1[gt], bv1[gt], bv1[gt], bv1[gt]};
            acc[0][gt] = s; acc[1][gt] = s;
        }
#pragma unroll
        for (int ks = 0; ks < 4; ++ks) {
            int cc = ks*4 + quad;
            bf16x8 a0 = *(const bf16x8*)&h0wr[lrow*128      + ((cc ^ lrow)*8)];
            bf16x8 a1 = *(const bf16x8*)&h0wr[(16+lrow)*128 + ((cc ^ lrow)*8)];
#pragma unroll
            for (int gt = 0; gt < 4; ++gt) {
                MFMA(acc[0][gt], a0, w1h[ks*4+gt]);
                MFMA(acc[1][gt], a1, w1h[ks*4+gt]);
            }
        }
#pragma unroll
        for (int ks = 0; ks < 4; ++ks) {
            int cc = ks*4 + quad;
            bf16x8 a0 = *(const bf16x8*)&h1s[lrow*128      + ((cc ^ lrow)*8)];
            bf16x8 a1 = *(const bf16x8*)&h1s[(16+lrow)*128 + ((cc ^ lrow)*8)];
#pragma unroll
            for (int gt = 0; gt < 4; ++gt) {
                bf16x8 bf = *(const bf16x8*)&wl[ut*8192 + (ks*4+gt)*512 + lane*8];
                MFMA(acc[0][gt], a0, bf);
                MFMA(acc[1][gt], a1, bf);
            }
        }
        __syncthreads();
#pragma unroll
        for (int m = 0; m < 2; ++m) {
#pragma unroll
            for (int r = 0; r < 4; r += 2) {
                float hv[2];
#pragma unroll
                for (int q = 0; q < 2; ++q) {
                    float ig = sigm(acc[m][0][r+q]);
                    float fg = sigm(acc[m][1][r+q]);
                    float gg = tanhf_(acc[m][2][r+q]);
                    float og = sigm(acc[m][3][r+q]);
                    float c  = fg * c1[m][r+q] + ig * gg;
                    c1[m][r+q] = c;
                    hv[q] = og * tanhf_(c);
                }
                unsigned u = pkbf2(hv[0], hv[1]);
                int b0 = m*16 + quad*4 + r;
                h1s[b0*128     + ((jc ^ (b0&15))*8)     + jl] = (unsigned short)u;
                h1s[(b0+1)*128 + ((jc ^ ((b0+1)&15))*8) + jl] = (unsigned short)(u >> 16);
            }
        }
    };
#pragma unroll 1
    for (int t2 = 0; t2 < T_SEQ/2; ++t2) {
        step(h0s[0], h0s[1], 2*t2);
        step(h0s[1], h0s[0], 2*t2 + 1);
    }
    __syncthreads();
    float* lg = (float*)&h0s[0][0];
    if (tid < 320) {
        int c = tid >> 5, b = tid & 31;
        float s = bfc[c];
        const float* wr = Wfc + c*H;
#pragma unroll 4
        for (int j = 0; j < H; ++j)
            s = fmaf(wr[j], bf2f(h1s[b*128 + (((j>>3) ^ (b&15))*8) + (j&7)]), s);
        lg[c*32 + b] = s;
    }
    __syncthreads();
    if (tid < 32) {
        int b = tid;
        float m = -1e30f;
#pragma unroll
        for (int c = 0; c < 10; ++c) m = fmaxf(m, lg[c*32 + b]);
        float ssum = 0.f;
#pragma unroll
        for (int c = 0; c < 10; ++c) ssum += __expf(lg[c*32 + b] - m);
        float ls = m + __logf(ssum);
        float* op = out + (size_t)(bbase + b) * 10;
#pragma unroll
        for (int c = 0; c < 10; ++c) op[c] = lg[c*32 + b] - ls;
    }
}

extern "C" void kernel_launch(void* const* d_in, const int* in_sizes, int n_in,
                              void* d_out, int out_size, void* d_ws, size_t ws_size,
                              hipStream_t stream) {
    const float* x    = (const float*)d_in[0];
    const float* Wih0 = (const float*)d_in[1];
    const float* Whh0 = (const float*)d_in[2];
    const float* bih0 = (const float*)d_in[3];
    const float* bhh0 = (const float*)d_in[4];
    const float* Wih1 = (const float*)d_in[5];
    const float* Whh1 = (const float*)d_in[6];
    const float* bih1 = (const float*)d_in[7];
    const float* bhh1 = (const float*)d_in[8];
    const float* Wfc  = (const float*)d_in[9];
    const float* bfc  = (const float*)d_in[10];
    float* out = (float*)d_out;

    unsigned short* W = (unsigned short*)d_ws;
    float* bias = (float*)((char*)d_ws + BIAS_OFF_BYTES);

    const int n_prep = NW0E + NW1E + 1024;
    prep<<<(n_prep + 255) / 256, 256, 0, stream>>>(Wih0, Whh0, bih0, bhh0,
                                                   Wih1, Whh1, bih1, bhh1, W, bias);
    if (ws_size >= (size_t)NEED_WS) {
        unsigned short* h0seq = (unsigned short*)((char*)d_ws + SEQ_OFF_BYTES);
        lstm_l0<<<512, NTHR, 0, stream>>>(x, W, bias, h0seq);
        lstm_l1<<<256, NTHR, 0, stream>>>(h0seq, W, bias, Wfc, bfc, out);
    } else {
        lstm_mfma<<<256, NTHR, 0, stream>>>(x, W, bias, Wfc, bfc, out);
    }
}